// Round 3
// baseline (1506.247 us; speedup 1.0000x reference)
//
#include <hip/hip_runtime.h>
#include <hip/hip_bf16.h>

#define HID 64
#define NGRAPH 16

// Workspace layout (float offsets)
enum : int {
  OFF_POOLED = 0,                     // [16*64]
  OFF_CNT    = 1024,                  // [16]
  OFF_V      = 1040,                  // [64]   v = eb2 @ nw1[1:]
  OFF_M      = 1104,                  // [4096] M = ew2 @ nw1[1:]
  OFF_EW1    = 5200,                  // [320]
  OFF_EB1    = 5520,                  // [64]
  OFF_NW1    = 5584,                  // [4160]
  OFF_NB1    = 9744,                  // [64]
  OFF_NW2    = 9808,                  // [4096]
  OFF_NB2    = 13904,                 // [64]
  OFF_OW1    = 13968,                 // [4096]
  OFF_OB1    = 18064,                 // [64]
  OFF_OW2    = 18128,                 // [4096]
  OFF_OB2    = 22224,                 // [64]
  OFF_OW3    = 22288,                 // [4096]
  OFF_OB3    = 26384,                 // [64]
  OFF_OW4    = 26448,                 // [128]
  OFF_OB4    = 26576,                 // [2]
  OFF_EW2    = 26578,                 // [4096]
  OFF_EB2    = 30674,                 // [64]
  OFF_FLAGS  = 30738,                 // 2 ints: [0]=ft (1=bf16), [1]=it (1=int64)
  OFF_CHUNK  = 30740                  // aggChunk[C*64] then degChunk[C]
};

struct WPtrs { const void* p[16]; };

__device__ __forceinline__ float cv(float v) { return v; }
__device__ __forceinline__ float cv(__hip_bfloat16 v) { return __bfloat162float(v); }

// ---------------------------------------------------------------------------
// prep: detect dtypes, convert all weights to fp32 in ws, build folded M, v.
// Single block of 256 threads.
// ---------------------------------------------------------------------------
__global__ __launch_bounds__(256) void prep_kernel(
    const void* xv, const void* eiv, WPtrs wp, float* ws)
{
  __shared__ int red[2];
  __shared__ int s_ft;
  const int t = threadIdx.x;

  if (t == 0) { red[0] = 0; red[1] = 0; }
  __syncthreads();

  // FT detect: fp32 storage => low 16 bits are random mantissa => ~45% of
  // low-halves, decoded as bf16, have exponent field >= 140 (|v| >= 2^13,
  // impossible for genuine N(0,1) data). bf16 storage => 0 such words.
  {
    const unsigned* u = (const unsigned*)xv;
    int big = 0;
    for (int i = t; i < 512; i += 256) {
      const unsigned el = (u[i] >> 7) & 0xFFu;
      big += (el >= 140u) ? 1 : 0;
    }
    atomicAdd(&red[0], big);
  }
  // IT detect: int64 storage => odd int32 words (high halves) all zero.
  {
    const int* e32 = (const int*)eiv;
    int orv = 0;
    for (int i = 1 + 2 * t; i < 2048; i += 512) orv |= e32[i];
    atomicOr(&red[1], orv);
  }
  __syncthreads();
  if (t == 0) {
    const int ft = (red[0] < 8) ? 1 : 0;
    const int it = (red[1] == 0) ? 1 : 0;
    ((int*)(ws + OFF_FLAGS))[0] = ft;
    ((int*)(ws + OFF_FLAGS))[1] = it;
    s_ft = ft;
  }
  __syncthreads();
  const int ft = s_ft;

  // Convert the 16 weight arrays (d_in[4..19]) to fp32.
  const int sz[16]  = {320,64,4096,64,4160,64,4096,64,4096,64,4096,64,4096,64,128,2};
  const int dst[16] = {OFF_EW1,OFF_EB1,OFF_EW2,OFF_EB2,OFF_NW1,OFF_NB1,OFF_NW2,OFF_NB2,
                       OFF_OW1,OFF_OB1,OFF_OW2,OFF_OB2,OFF_OW3,OFF_OB3,OFF_OW4,OFF_OB4};
  for (int a = 0; a < 16; ++a) {
    const void* src = wp.p[a];
    float* d = ws + dst[a];
    const int n = sz[a];
    for (int i = t; i < n; i += 256)
      d[i] = ft ? __bfloat162float(((const __hip_bfloat16*)src)[i])
                : ((const float*)src)[i];
  }
  __syncthreads();

  // Stage ew2, nw1[1:] in LDS, then build M[i][j] = sum_k ew2[i][k]*nw1[1+k][j]
  __shared__ float ew2s[4096];
  __shared__ float nw1s[4096];
  for (int i = t; i < 4096; i += 256) {
    ew2s[i] = ws[OFF_EW2 + i];
    nw1s[i] = ws[OFF_NW1 + 64 + i];   // rows 1..64
  }
  __syncthreads();
  for (int idx = t; idx < 4096; idx += 256) {
    const int i = idx >> 6, j = idx & 63;
    float s = 0.0f;
    #pragma unroll 8
    for (int k = 0; k < 64; ++k)
      s = fmaf(ew2s[i * 64 + k], nw1s[k * 64 + j], s);
    ws[OFF_M + idx] = s;
  }
  for (int j = t; j < 64; j += 256) {
    float s = 0.0f;
    #pragma unroll 8
    for (int k = 0; k < 64; ++k)
      s = fmaf(ws[OFF_EB2 + k], nw1s[k * 64 + j], s);
    ws[OFF_V + j] = s;
  }
}

// ---------------------------------------------------------------------------
// Edge pass: one wave per edge (grid-stride); lane j = relu-hidden feature j.
// Only edges with col in [lo,hi) do work; coalesced 256B atomic into aggChunk.
// ---------------------------------------------------------------------------
template<typename FT, typename IT>
__device__ __forceinline__ void edge_impl(
    const FT* __restrict__ x, const IT* __restrict__ ei, const FT* __restrict__ ea,
    const float* __restrict__ ws, float* __restrict__ aggC, float* __restrict__ degC,
    const int lo, const int hi, const int E)
{
  const int lane = threadIdx.x & 63;
  const int wid  = blockIdx.x * (blockDim.x >> 6) + (threadIdx.x >> 6);
  const int nwv  = gridDim.x * (blockDim.x >> 6);

  const float w0 = ws[OFF_EW1 + 0 * HID + lane];
  const float w1 = ws[OFF_EW1 + 1 * HID + lane];
  const float w2 = ws[OFF_EW1 + 2 * HID + lane];
  const float w3 = ws[OFF_EW1 + 3 * HID + lane];
  const float w4 = ws[OFF_EW1 + 4 * HID + lane];
  const float b0 = ws[OFF_EB1 + lane];

  for (int e = wid; e < E; e += nwv) {
    const int c = (int)ei[(size_t)E + e];
    if (c < lo || c >= hi) continue;
    const int r = (int)ei[e];
    const float xr = cv(x[r]);
    const float xc = cv(x[c]);
    const float a0 = cv(ea[(size_t)3 * e + 0]);
    const float a1 = cv(ea[(size_t)3 * e + 1]);
    const float a2 = cv(ea[(size_t)3 * e + 2]);
    float h = fmaf(xr, w0, fmaf(xc, w1, fmaf(a0, w2, fmaf(a1, w3, fmaf(a2, w4, b0)))));
    h = fmaxf(h, 0.0f);
    unsafeAtomicAdd(&aggC[(size_t)(c - lo) * HID + lane], h);
    if (lane == 0) unsafeAtomicAdd(&degC[c - lo], 1.0f);
  }
}

__global__ __launch_bounds__(256) void edge_pass(
    const void* xv, const void* eiv, const void* eav, float* ws,
    const int lo, const int hi, const int E, const int C)
{
  float* aggC = ws + OFF_CHUNK;
  float* degC = aggC + (size_t)C * HID;
  const int* fl = (const int*)(ws + OFF_FLAGS);
  const int ft = fl[0], it = fl[1];
  if (ft) {
    if (it) edge_impl<__hip_bfloat16, long long>((const __hip_bfloat16*)xv, (const long long*)eiv, (const __hip_bfloat16*)eav, ws, aggC, degC, lo, hi, E);
    else    edge_impl<__hip_bfloat16, int>((const __hip_bfloat16*)xv, (const int*)eiv, (const __hip_bfloat16*)eav, ws, aggC, degC, lo, hi, E);
  } else {
    if (it) edge_impl<float, long long>((const float*)xv, (const long long*)eiv, (const float*)eav, ws, aggC, degC, lo, hi, E);
    else    edge_impl<float, int>((const float*)xv, (const int*)eiv, (const float*)eav, ws, aggC, degC, lo, hi, E);
  }
}

// ---------------------------------------------------------------------------
// Node pass for chunk [lo,hi):
//   h = relu(x[n]*nw1[0,:] + aggC[n]@M + deg[n]*v + nb1)
//   atomic-accumulate h into pooledH[batch[n]], count into cnt.
// ---------------------------------------------------------------------------
template<typename FT, typename IT>
__device__ __forceinline__ void node_impl(
    const FT* __restrict__ x, const IT* __restrict__ batch, float* __restrict__ ws,
    const float* __restrict__ aggC, const float* __restrict__ degC,
    const float* __restrict__ Msh, const int lo, const int hi)
{
  const int t = threadIdx.x;
  const int lane = t & 63;
  const float c1 = ws[OFF_NW1 + lane];   // nw1[0][lane]
  const float bb = ws[OFF_NB1 + lane];
  const float vv = ws[OFF_V + lane];
  float* pooled = ws + OFF_POOLED;
  float* cntp   = ws + OFF_CNT;

  const int wid = blockIdx.x * (blockDim.x >> 6) + (t >> 6);
  const int nwv = gridDim.x * (blockDim.x >> 6);

  for (int n0 = lo + wid * 2; n0 < hi; n0 += nwv * 2) {
    const int n1 = n0 + 1;
    const bool ok1 = n1 < hi;
    const float a0 = aggC[(size_t)(n0 - lo) * HID + lane];
    const float a1 = ok1 ? aggC[(size_t)(n1 - lo) * HID + lane] : 0.0f;
    float acc0 = 0.0f, acc1 = 0.0f;
    #pragma unroll 16
    for (int k = 0; k < 64; ++k) {
      const float w = Msh[k * 64 + lane];
      acc0 = fmaf(__shfl(a0, k), w, acc0);
      acc1 = fmaf(__shfl(a1, k), w, acc1);
    }
    {
      const float h = fmaxf(acc0 + cv(x[n0]) * c1 + degC[n0 - lo] * vv + bb, 0.0f);
      const int g = (int)batch[n0];
      unsafeAtomicAdd(&pooled[g * HID + lane], h);
      if (lane == 0) unsafeAtomicAdd(&cntp[g], 1.0f);
    }
    if (ok1) {
      const float h = fmaxf(acc1 + cv(x[n1]) * c1 + degC[n1 - lo] * vv + bb, 0.0f);
      const int g = (int)batch[n1];
      unsafeAtomicAdd(&pooled[g * HID + lane], h);
      if (lane == 0) unsafeAtomicAdd(&cntp[g], 1.0f);
    }
  }
}

__global__ __launch_bounds__(256) void node_pass(
    const void* xv, const void* batv, float* ws,
    const int lo, const int hi, const int C)
{
  __shared__ float Msh[4096];
  for (int i = threadIdx.x; i < 4096; i += blockDim.x) Msh[i] = ws[OFF_M + i];
  __syncthreads();

  const float* aggC = ws + OFF_CHUNK;
  const float* degC = aggC + (size_t)C * HID;
  const int* fl = (const int*)(ws + OFF_FLAGS);
  const int ft = fl[0], it = fl[1];
  if (ft) {
    if (it) node_impl<__hip_bfloat16, long long>((const __hip_bfloat16*)xv, (const long long*)batv, ws, aggC, degC, Msh, lo, hi);
    else    node_impl<__hip_bfloat16, int>((const __hip_bfloat16*)xv, (const int*)batv, ws, aggC, degC, Msh, lo, hi);
  } else {
    if (it) node_impl<float, long long>((const float*)xv, (const long long*)batv, ws, aggC, degC, Msh, lo, hi);
    else    node_impl<float, int>((const float*)xv, (const int*)batv, ws, aggC, degC, Msh, lo, hi);
  }
}

// ---------------------------------------------------------------------------
// Head: pooled = pooledH @ nw2 + cnt*nb2, 3x (Linear+ReLU), Linear(64,2).
// Output dtype follows detected float dtype.
// ---------------------------------------------------------------------------
__global__ __launch_bounds__(256) void head_kernel(float* ws, void* outv)
{
  __shared__ float A[NGRAPH][HID];
  __shared__ float B[NGRAPH][HID];

  const int t = threadIdx.x;
  const int j = t & 63;
  const int gq = t >> 6;  // 0..3

  {
    const float bj = ws[OFF_NB2 + j];
    #pragma unroll
    for (int gi = 0; gi < 4; ++gi) {
      const int g = gq + gi * 4;
      float s = ws[OFF_CNT + g] * bj;
      #pragma unroll 8
      for (int k = 0; k < HID; ++k)
        s = fmaf(ws[OFF_POOLED + g * HID + k], ws[OFF_NW2 + k * HID + j], s);
      A[g][j] = s;
    }
  }
  __syncthreads();

  const int wOff[3] = {OFF_OW1, OFF_OW2, OFF_OW3};
  const int bOff[3] = {OFF_OB1, OFF_OB2, OFF_OB3};
  for (int L = 0; L < 3; ++L) {
    float (*In)[HID]  = (L & 1) ? B : A;
    float (*Out)[HID] = (L & 1) ? A : B;
    const float bj = ws[bOff[L] + j];
    #pragma unroll
    for (int gi = 0; gi < 4; ++gi) {
      const int g = gq + gi * 4;
      float s = bj;
      #pragma unroll 8
      for (int k = 0; k < HID; ++k)
        s = fmaf(In[g][k], ws[wOff[L] + k * HID + j], s);
      Out[g][j] = fmaxf(s, 0.0f);
    }
    __syncthreads();
  }

  // After 3 layers result is in B (L=2 wrote Out=B). Final Linear(64,2).
  if (t < 32) {
    const int g = t >> 1, d = t & 1;
    float s = ws[OFF_OB4 + d];
    #pragma unroll 8
    for (int k = 0; k < HID; ++k)
      s = fmaf(B[g][k], ws[OFF_OW4 + k * 2 + d], s);
    const int ft = ((const int*)(ws + OFF_FLAGS))[0];
    if (ft) ((__hip_bfloat16*)outv)[g * 2 + d] = __float2bfloat16(s);
    else    ((float*)outv)[g * 2 + d] = s;
  }
}

extern "C" void kernel_launch(void* const* d_in, const int* in_sizes, int n_in,
                              void* d_out, int out_size, void* d_ws, size_t ws_size,
                              hipStream_t stream)
{
  const void* xv   = d_in[0];
  const void* eiv  = d_in[1];
  const void* eav  = d_in[2];
  const void* batv = d_in[3];

  WPtrs wp;
  for (int a = 0; a < 16; ++a) wp.p[a] = d_in[4 + a];

  const int N = in_sizes[0];
  const int E = in_sizes[1] / 2;

  float* ws = (float*)d_ws;
  const size_t fixedBytes = (size_t)OFF_CHUNK * sizeof(float);
  const size_t perNode = (HID + 1) * sizeof(float);
  if (ws_size < fixedBytes + 64 * perNode) return;  // unusable scratch

  long long Cll = (long long)((ws_size - fixedBytes) / perNode);
  int C = (int)(Cll > N ? N : Cll);
  C &= ~63;
  if (C < 64) return;
  const int passes = (N + C - 1) / C;

  // zero pooledH + cnt (ws is poisoned 0xAA before every call)
  hipMemsetAsync(ws, 0, (size_t)(OFF_CNT + NGRAPH) * sizeof(float), stream);

  prep_kernel<<<1, 256, 0, stream>>>(xv, eiv, wp, ws);

  for (int p = 0; p < passes; ++p) {
    const int lo = p * C;
    const int hi = (lo + C < N) ? (lo + C) : N;
    hipMemsetAsync(ws + OFF_CHUNK, 0, (size_t)C * perNode, stream);
    edge_pass<<<1024, 256, 0, stream>>>(xv, eiv, eav, ws, lo, hi, E, C);
    node_pass<<<256, 256, 0, stream>>>(xv, batv, ws, lo, hi, C);
  }

  head_kernel<<<1, 256, 0, stream>>>(ws, d_out);
}

// Round 4
// 854.959 us; speedup vs baseline: 1.7618x; 1.7618x over previous
//
#include <hip/hip_runtime.h>
#include <hip/hip_bf16.h>

#define HID 64
#define NGRAPH 16

// Workspace layout (float offsets)
enum : int {
  OFF_POOLED = 0,                     // [16*64]
  OFF_CNT    = 1024,                  // [16]
  OFF_V      = 1040,                  // [64]   v = eb2 @ nw1[1:]
  OFF_M      = 1104,                  // [4096] M = ew2 @ nw1[1:]
  OFF_EW1    = 5200,                  // [320]
  OFF_EB1    = 5520,                  // [64]
  OFF_NW1    = 5584,                  // [4160]
  OFF_NB1    = 9744,                  // [64]
  OFF_NW2    = 9808,                  // [4096]
  OFF_NB2    = 13904,                 // [64]
  OFF_OW1    = 13968,                 // [4096]
  OFF_OB1    = 18064,                 // [64]
  OFF_OW2    = 18128,                 // [4096]
  OFF_OB2    = 22224,                 // [64]
  OFF_OW3    = 22288,                 // [4096]
  OFF_OB3    = 26384,                 // [64]
  OFF_OW4    = 26448,                 // [128]
  OFF_OB4    = 26576,                 // [2]
  OFF_EW2    = 26578,                 // [4096]
  OFF_EB2    = 30674,                 // [64]
  OFF_FLAGS  = 30738,                 // 2 ints: [0]=ft (1=bf16), [1]=it (1=int64)
  OFF_CHUNK  = 30740                  // aggChunk[C*64] then degChunk[C]
};

struct WPtrs { const void* p[16]; };

__device__ __forceinline__ float cv(float v) { return v; }
__device__ __forceinline__ float cv(__hip_bfloat16 v) { return __bfloat162float(v); }

// ---------------------------------------------------------------------------
// prep: detect dtypes, convert all weights to fp32 in ws, build folded M, v.
// ---------------------------------------------------------------------------
__global__ __launch_bounds__(256) void prep_kernel(
    const void* xv, const void* eiv, WPtrs wp, float* ws)
{
  __shared__ int red[2];
  __shared__ int s_ft;
  const int t = threadIdx.x;

  if (t == 0) { red[0] = 0; red[1] = 0; }
  __syncthreads();

  // FT detect: fp32 storage => ~45% of low-half words decode as bf16 with
  // exponent >= 2^13 (impossible for N(0,1) data); bf16 storage => none.
  {
    const unsigned* u = (const unsigned*)xv;
    int big = 0;
    for (int i = t; i < 512; i += 256) {
      const unsigned el = (u[i] >> 7) & 0xFFu;
      big += (el >= 140u) ? 1 : 0;
    }
    atomicAdd(&red[0], big);
  }
  // IT detect: int64 storage => odd int32 words all zero.
  {
    const int* e32 = (const int*)eiv;
    int orv = 0;
    for (int i = 1 + 2 * t; i < 2048; i += 512) orv |= e32[i];
    atomicOr(&red[1], orv);
  }
  __syncthreads();
  if (t == 0) {
    const int ft = (red[0] < 8) ? 1 : 0;
    const int it = (red[1] == 0) ? 1 : 0;
    ((int*)(ws + OFF_FLAGS))[0] = ft;
    ((int*)(ws + OFF_FLAGS))[1] = it;
    s_ft = ft;
  }
  __syncthreads();
  const int ft = s_ft;

  const int sz[16]  = {320,64,4096,64,4160,64,4096,64,4096,64,4096,64,4096,64,128,2};
  const int dst[16] = {OFF_EW1,OFF_EB1,OFF_EW2,OFF_EB2,OFF_NW1,OFF_NB1,OFF_NW2,OFF_NB2,
                       OFF_OW1,OFF_OB1,OFF_OW2,OFF_OB2,OFF_OW3,OFF_OB3,OFF_OW4,OFF_OB4};
  for (int a = 0; a < 16; ++a) {
    const void* src = wp.p[a];
    float* d = ws + dst[a];
    const int n = sz[a];
    for (int i = t; i < n; i += 256)
      d[i] = ft ? __bfloat162float(((const __hip_bfloat16*)src)[i])
                : ((const float*)src)[i];
  }
  __syncthreads();

  __shared__ float ew2s[4096];
  __shared__ float nw1s[4096];
  for (int i = t; i < 4096; i += 256) {
    ew2s[i] = ws[OFF_EW2 + i];
    nw1s[i] = ws[OFF_NW1 + 64 + i];   // rows 1..64
  }
  __syncthreads();
  for (int idx = t; idx < 4096; idx += 256) {
    const int i = idx >> 6, j = idx & 63;
    float s = 0.0f;
    #pragma unroll 8
    for (int k = 0; k < 64; ++k)
      s = fmaf(ew2s[i * 64 + k], nw1s[k * 64 + j], s);
    ws[OFF_M + idx] = s;
  }
  for (int j = t; j < 64; j += 256) {
    float s = 0.0f;
    #pragma unroll 8
    for (int k = 0; k < 64; ++k)
      s = fmaf(ws[OFF_EB2 + k], nw1s[k * 64 + j], s);
    ws[OFF_V + j] = s;
  }
}

// ---------------------------------------------------------------------------
// deg pass: per-lane grid-stride over edges, coalesced col reads, scattered
// f32 atomics into degC. Separate dispatch so its cost is profiled alone.
// ---------------------------------------------------------------------------
template<typename IT>
__device__ __forceinline__ void deg_impl(
    const IT* __restrict__ ei, float* __restrict__ degC,
    const int lo, const int hi, const int E)
{
  const int tid = blockIdx.x * blockDim.x + threadIdx.x;
  const int nth = gridDim.x * blockDim.x;
  for (int e = tid; e < E; e += nth) {
    const int c = (int)ei[(size_t)E + e];
    if (c >= lo && c < hi) unsafeAtomicAdd(&degC[c - lo], 1.0f);
  }
}

__global__ __launch_bounds__(256) void deg_pass(
    const void* eiv, float* ws, const int lo, const int hi, const int E, const int C)
{
  float* degC = ws + OFF_CHUNK + (size_t)C * HID;
  const int it = ((const int*)(ws + OFF_FLAGS))[1];
  if (it) deg_impl<long long>((const long long*)eiv, degC, lo, hi, E);
  else    deg_impl<int>((const int*)eiv, degC, lo, hi, E);
}

// ---------------------------------------------------------------------------
// Edge pass: one wave per edge; lane j = relu-hidden feature j; 4-edge ILP.
// Single coalesced 256B wave-atomic per edge into aggC. No deg atomics here.
// ---------------------------------------------------------------------------
template<typename FT, typename IT>
__device__ __forceinline__ void edge_impl(
    const FT* __restrict__ x, const IT* __restrict__ ei, const FT* __restrict__ ea,
    const float* __restrict__ ws, float* __restrict__ aggC,
    const int lo, const int hi, const int E)
{
  const int lane = threadIdx.x & 63;
  const int wid  = blockIdx.x * (blockDim.x >> 6) + (threadIdx.x >> 6);
  const int nwv  = gridDim.x * (blockDim.x >> 6);

  const float w0 = ws[OFF_EW1 + 0 * HID + lane];
  const float w1 = ws[OFF_EW1 + 1 * HID + lane];
  const float w2 = ws[OFF_EW1 + 2 * HID + lane];
  const float w3 = ws[OFF_EW1 + 3 * HID + lane];
  const float w4 = ws[OFF_EW1 + 4 * HID + lane];
  const float b0 = ws[OFF_EB1 + lane];

  for (int e0 = wid * 4; e0 < E; e0 += nwv * 4) {
    int   r[4], c[4];
    float xr[4], xc[4], a0[4], a1[4], a2[4];
    bool  ok[4];
    #pragma unroll
    for (int i = 0; i < 4; ++i) {
      const int e = e0 + i;
      ok[i] = (e < E);
      const int ee = ok[i] ? e : 0;
      r[i] = (int)ei[ee];
      c[i] = (int)ei[(size_t)E + ee];
    }
    #pragma unroll
    for (int i = 0; i < 4; ++i) {
      xr[i] = cv(x[r[i]]);
      xc[i] = cv(x[c[i]]);
      const int e = ok[i] ? (e0 + i) : 0;
      a0[i] = cv(ea[(size_t)3 * e + 0]);
      a1[i] = cv(ea[(size_t)3 * e + 1]);
      a2[i] = cv(ea[(size_t)3 * e + 2]);
    }
    #pragma unroll
    for (int i = 0; i < 4; ++i) {
      float h = fmaf(xr[i], w0, fmaf(xc[i], w1,
                fmaf(a0[i], w2, fmaf(a1[i], w3, fmaf(a2[i], w4, b0)))));
      h = fmaxf(h, 0.0f);
      if (ok[i] && c[i] >= lo && c[i] < hi)
        unsafeAtomicAdd(&aggC[(size_t)(c[i] - lo) * HID + lane], h);
    }
  }
}

__global__ __launch_bounds__(256) void edge_pass(
    const void* xv, const void* eiv, const void* eav, float* ws,
    const int lo, const int hi, const int E, const int C)
{
  float* aggC = ws + OFF_CHUNK;
  const int* fl = (const int*)(ws + OFF_FLAGS);
  const int ft = fl[0], it = fl[1];
  if (ft) {
    if (it) edge_impl<__hip_bfloat16, long long>((const __hip_bfloat16*)xv, (const long long*)eiv, (const __hip_bfloat16*)eav, ws, aggC, lo, hi, E);
    else    edge_impl<__hip_bfloat16, int>((const __hip_bfloat16*)xv, (const int*)eiv, (const __hip_bfloat16*)eav, ws, aggC, lo, hi, E);
  } else {
    if (it) edge_impl<float, long long>((const float*)xv, (const long long*)eiv, (const float*)eav, ws, aggC, lo, hi, E);
    else    edge_impl<float, int>((const float*)xv, (const int*)eiv, (const float*)eav, ws, aggC, lo, hi, E);
  }
}

// ---------------------------------------------------------------------------
// Node pass for chunk [lo,hi): contiguous node range per wave; batch is
// SORTED, so pooled accumulation lives in registers and flushes only on
// graph-boundary crossings (~1-2 global wave-atomics per wave total).
//   h = relu(x[n]*nw1[0,:] + aggC[n]@M + deg[n]*v + nb1)
// ---------------------------------------------------------------------------
template<typename FT, typename IT>
__device__ __forceinline__ void node_impl(
    const FT* __restrict__ x, const IT* __restrict__ batch, float* __restrict__ ws,
    const float* __restrict__ aggC, const float* __restrict__ degC,
    const float* __restrict__ Msh, const int lo, const int hi)
{
  const int t = threadIdx.x;
  const int lane = t & 63;
  const float c1 = ws[OFF_NW1 + lane];   // nw1[0][lane]
  const float bb = ws[OFF_NB1 + lane];
  const float vv = ws[OFF_V + lane];
  float* pooled = ws + OFF_POOLED;
  float* cntp   = ws + OFF_CNT;

  const int wid = blockIdx.x * (blockDim.x >> 6) + (t >> 6);
  const int W   = gridDim.x * (blockDim.x >> 6);

  const int total = hi - lo;
  const int per = (total + W - 1) / W;
  const int a = lo + wid * per;
  const int b = (a + per < hi) ? (a + per) : hi;

  float accp = 0.0f, cntl = 0.0f;
  int curg = -1;

  for (int n = a; n < b; ++n) {
    const float av = aggC[(size_t)(n - lo) * HID + lane];
    float acc = 0.0f;
    #pragma unroll 16
    for (int k = 0; k < 64; ++k)
      acc = fmaf(__shfl(av, k), Msh[k * 64 + lane], acc);
    const float h = fmaxf(acc + cv(x[n]) * c1 + degC[n - lo] * vv + bb, 0.0f);
    const int g = (int)batch[n];
    if (g != curg) {
      if (curg >= 0) {
        unsafeAtomicAdd(&pooled[curg * HID + lane], accp);
        if (lane == 0) unsafeAtomicAdd(&cntp[curg], cntl);
      }
      curg = g; accp = 0.0f; cntl = 0.0f;
    }
    accp += h; cntl += 1.0f;
  }
  if (curg >= 0) {
    unsafeAtomicAdd(&pooled[curg * HID + lane], accp);
    if (lane == 0) unsafeAtomicAdd(&cntp[curg], cntl);
  }
}

__global__ __launch_bounds__(256) void node_pass(
    const void* xv, const void* batv, float* ws,
    const int lo, const int hi, const int C)
{
  __shared__ float Msh[4096];
  for (int i = threadIdx.x; i < 4096; i += blockDim.x) Msh[i] = ws[OFF_M + i];
  __syncthreads();

  const float* aggC = ws + OFF_CHUNK;
  const float* degC = aggC + (size_t)C * HID;
  const int* fl = (const int*)(ws + OFF_FLAGS);
  const int ft = fl[0], it = fl[1];
  if (ft) {
    if (it) node_impl<__hip_bfloat16, long long>((const __hip_bfloat16*)xv, (const long long*)batv, ws, aggC, degC, Msh, lo, hi);
    else    node_impl<__hip_bfloat16, int>((const __hip_bfloat16*)xv, (const int*)batv, ws, aggC, degC, Msh, lo, hi);
  } else {
    if (it) node_impl<float, long long>((const float*)xv, (const long long*)batv, ws, aggC, degC, Msh, lo, hi);
    else    node_impl<float, int>((const float*)xv, (const int*)batv, ws, aggC, degC, Msh, lo, hi);
  }
}

// ---------------------------------------------------------------------------
// Head: pooled = pooledH @ nw2 + cnt*nb2, 3x (Linear+ReLU), Linear(64,2).
// ---------------------------------------------------------------------------
__global__ __launch_bounds__(256) void head_kernel(float* ws, void* outv)
{
  __shared__ float A[NGRAPH][HID];
  __shared__ float B[NGRAPH][HID];

  const int t = threadIdx.x;
  const int j = t & 63;
  const int gq = t >> 6;  // 0..3

  {
    const float bj = ws[OFF_NB2 + j];
    #pragma unroll
    for (int gi = 0; gi < 4; ++gi) {
      const int g = gq + gi * 4;
      float s = ws[OFF_CNT + g] * bj;
      #pragma unroll 8
      for (int k = 0; k < HID; ++k)
        s = fmaf(ws[OFF_POOLED + g * HID + k], ws[OFF_NW2 + k * HID + j], s);
      A[g][j] = s;
    }
  }
  __syncthreads();

  const int wOff[3] = {OFF_OW1, OFF_OW2, OFF_OW3};
  const int bOff[3] = {OFF_OB1, OFF_OB2, OFF_OB3};
  for (int L = 0; L < 3; ++L) {
    float (*In)[HID]  = (L & 1) ? B : A;
    float (*Out)[HID] = (L & 1) ? A : B;
    const float bj = ws[bOff[L] + j];
    #pragma unroll
    for (int gi = 0; gi < 4; ++gi) {
      const int g = gq + gi * 4;
      float s = bj;
      #pragma unroll 8
      for (int k = 0; k < HID; ++k)
        s = fmaf(In[g][k], ws[wOff[L] + k * HID + j], s);
      Out[g][j] = fmaxf(s, 0.0f);
    }
    __syncthreads();
  }

  if (t < 32) {
    const int g = t >> 1, d = t & 1;
    float s = ws[OFF_OB4 + d];
    #pragma unroll 8
    for (int k = 0; k < HID; ++k)
      s = fmaf(B[g][k], ws[OFF_OW4 + k * 2 + d], s);
    const int ft = ((const int*)(ws + OFF_FLAGS))[0];
    if (ft) ((__hip_bfloat16*)outv)[g * 2 + d] = __float2bfloat16(s);
    else    ((float*)outv)[g * 2 + d] = s;
  }
}

extern "C" void kernel_launch(void* const* d_in, const int* in_sizes, int n_in,
                              void* d_out, int out_size, void* d_ws, size_t ws_size,
                              hipStream_t stream)
{
  const void* xv   = d_in[0];
  const void* eiv  = d_in[1];
  const void* eav  = d_in[2];
  const void* batv = d_in[3];

  WPtrs wp;
  for (int a = 0; a < 16; ++a) wp.p[a] = d_in[4 + a];

  const int N = in_sizes[0];
  const int E = in_sizes[1] / 2;

  float* ws = (float*)d_ws;
  const size_t fixedBytes = (size_t)OFF_CHUNK * sizeof(float);
  const size_t perNode = (HID + 1) * sizeof(float);
  if (ws_size < fixedBytes + 64 * perNode) return;

  long long Cll = (long long)((ws_size - fixedBytes) / perNode);
  int C = (int)(Cll > N ? N : Cll);
  C &= ~63;
  if (C < 64) return;
  const int passes = (N + C - 1) / C;

  hipMemsetAsync(ws, 0, (size_t)(OFF_CNT + NGRAPH) * sizeof(float), stream);

  prep_kernel<<<1, 256, 0, stream>>>(xv, eiv, wp, ws);

  for (int p = 0; p < passes; ++p) {
    const int lo = p * C;
    const int hi = (lo + C < N) ? (lo + C) : N;
    hipMemsetAsync(ws + OFF_CHUNK, 0, (size_t)C * perNode, stream);
    edge_pass<<<2048, 256, 0, stream>>>(xv, eiv, eav, ws, lo, hi, E, C);
    deg_pass<<<1024, 256, 0, stream>>>(eiv, ws, lo, hi, E, C);
    node_pass<<<256, 256, 0, stream>>>(xv, batv, ws, lo, hi, C);
  }

  head_kernel<<<1, 256, 0, stream>>>(ws, d_out);
}